// Round 3
// baseline (10934.821 us; speedup 1.0000x reference)
//
#include <hip/hip_runtime.h>
#include <hip/hip_bf16.h>
#include <math.h>

// Problem constants (from reference)
#define T_WIN   3
#define N_NODES 50000
#define HID     128
#define E_PER_T 100000
#define NH      8
#define DK      16

// NOTE (R3): all float inputs and the output are FP32 (per reference dtypes).
// R1/R2 read them as bf16 -> fp32 mantissa bits reinterpreted as bf16 exponents
// -> NaN. Q/K/V are staged in ws as bf16 (bandwidth + ws-size), computed in fp32.

typedef __hip_bfloat16 bf16;

__device__ __forceinline__ float b2f(bf16 v) { return __bfloat162float(v); }

__device__ __forceinline__ void atomicMaxF(float* addr, float val) {
    int* ia = (int*)addr;
    int cur = __float_as_int(*addr);
    while (val > __int_as_float(cur)) {
        int old = atomicCAS(ia, cur, __float_as_int(val));
        if (old == cur) break;
        cur = old;
    }
}
__device__ __forceinline__ void atomicMinF(float* addr, float val) {
    int* ia = (int*)addr;
    int cur = __float_as_int(*addr);
    while (val < __int_as_float(cur)) {
        int old = atomicCAS(ia, cur, __float_as_int(val));
        if (old == cur) break;
        cur = old;
    }
}

// dot of 8 bf16 pairs packed in uint4 (bf16->f32 is a 16-bit shift)
__device__ __forceinline__ float dot8(uint4 a, uint4 b) {
    float s = 0.f;
    const unsigned* pa = (const unsigned*)&a;
    const unsigned* pb = (const unsigned*)&b;
#pragma unroll
    for (int i = 0; i < 4; ++i) {
        float alo = __uint_as_float(pa[i] << 16);
        float ahi = __uint_as_float(pa[i] & 0xffff0000u);
        float blo = __uint_as_float(pb[i] << 16);
        float bhi = __uint_as_float(pb[i] & 0xffff0000u);
        s += alo * blo + ahi * bhi;
    }
    return s;
}

// ---------------------------------------------------------------------------
// Kernel 1: O[r,:] = xrows[r,:] @ W + b  (fp32 in, bf16 out staging).
// Block = 256 threads handles 32 rows.
// ---------------------------------------------------------------------------
__global__ __launch_bounds__(256) void project_kernel(
    const float* __restrict__ xrows, const float* __restrict__ W,
    const float* __restrict__ b, bf16* __restrict__ O)
{
    __shared__ float xs[32][128];
    const int r0 = blockIdx.x * 32;
    const int tid = threadIdx.x;
    const int nrows = (N_NODES - r0 < 32) ? (N_NODES - r0) : 32;

    // 32 rows * 128 cols, float4 loads: 1024 float4's, 4 per thread
    for (int i = tid; i < 32 * 32; i += 256) {
        int r = i >> 5, c4 = i & 31;
        float4 v = (r < nrows) ? ((const float4*)xrows)[(size_t)(r0 + r) * 32 + c4]
                               : make_float4(0.f, 0.f, 0.f, 0.f);
        *(float4*)&xs[r][c4 * 4] = v;
    }
    __syncthreads();

    const int col = tid & 127;
    const int rg  = tid >> 7;  // 0/1

    float acc[16];
#pragma unroll
    for (int j = 0; j < 16; ++j) acc[j] = 0.f;
    for (int k = 0; k < 128; k += 4) {
        float w0 = W[(k + 0) * 128 + col];
        float w1 = W[(k + 1) * 128 + col];
        float w2 = W[(k + 2) * 128 + col];
        float w3 = W[(k + 3) * 128 + col];
#pragma unroll
        for (int j = 0; j < 16; ++j) {
            const float4 hv = *(const float4*)&xs[rg + 2 * j][k];
            acc[j] += hv.x * w0 + hv.y * w1 + hv.z * w2 + hv.w * w3;
        }
    }
    float bias = b[col];
#pragma unroll
    for (int j = 0; j < 16; ++j) {
        int r = rg + 2 * j;
        if (r < nrows)
            O[(size_t)(r0 + r) * 128 + col] = __float2bfloat16(acc[j] + bias);
    }
}

// ---------------------------------------------------------------------------
// Kernel 2: per-t_tar init of softmax stats and accumulators.
// ---------------------------------------------------------------------------
__global__ __launch_bounds__(256) void init_kernel(
    float* m_c, float* m_n, float* s_c, float* s_s, float* hat_c, float* hat_s)
{
    int i = blockIdx.x * 256 + threadIdx.x;
    if (i < N_NODES * NH) {
        m_c[i] = -1e30f;
        m_n[i] =  1e30f;
        s_c[i] = 0.f;
        s_s[i] = 0.f;
    }
    if (i < N_NODES * HID) { hat_c[i] = 0.f; hat_s[i] = 0.f; }
}

// ---------------------------------------------------------------------------
// Kernel 3: attention logits for ONE t_src chunk + running max/min atomics.
// ---------------------------------------------------------------------------
__global__ __launch_bounds__(256) void att_chunk_kernel(
    const bf16* __restrict__ Qt, const bf16* __restrict__ Kc,
    const int* __restrict__ ei_src, const int* __restrict__ ei_tar,
    float* __restrict__ att_chunk, float* m_c, float* m_n)
{
    int idx = blockIdx.x * 256 + threadIdx.x;
    if (idx >= E_PER_T * NH) return;
    int h = idx & 7;
    int e = idx >> 3;
    int src = ei_src[e];
    int tar = ei_tar[e];

    const uint4* qp = (const uint4*)(Qt + ((size_t)tar * HID + h * DK));
    const uint4* kp = (const uint4*)(Kc + ((size_t)src * HID + h * DK));
    uint4 q0 = qp[0], q1 = qp[1];
    uint4 k0 = kp[0], k1 = kp[1];
    float a = (dot8(q0, k0) + dot8(q1, k1)) * 0.25f;  // / sqrt(16)

    att_chunk[idx] = a;
    atomicMaxF(&m_c[tar * NH + h], a);
    atomicMinF(&m_n[tar * NH + h], a);
}

// ---------------------------------------------------------------------------
// Kernel 4: exp-sums over all chunks. m_s(spurious) == -m_n, so
// exp(-a - m_s) == exp(m_n - a).
// ---------------------------------------------------------------------------
__global__ __launch_bounds__(256) void sum_kernel(
    const float* __restrict__ att, const int* __restrict__ ei,
    const float* __restrict__ m_c, const float* __restrict__ m_n,
    float* s_c, float* s_s, int t_tar)
{
    int idx = blockIdx.x * 256 + threadIdx.x;
    int tot = (t_tar + 1) * E_PER_T * NH;
    if (idx >= tot) return;
    int h  = idx & 7;
    int eg = idx >> 3;
    int t_src = eg / E_PER_T;
    int e = eg - t_src * E_PER_T;
    int tar = ei[(t_src * 2 + 1) * E_PER_T + e];
    float a = att[idx];
    int nh = tar * NH + h;
    atomicAdd(&s_c[nh], __expf(a - m_c[nh]));
    atomicAdd(&s_s[nh], __expf(m_n[nh] - a));
}

// ---------------------------------------------------------------------------
// Kernel 5: weighted scatter of V (one t_src chunk) into accumulators.
// ---------------------------------------------------------------------------
__global__ __launch_bounds__(256) void agg_chunk_kernel(
    const float* __restrict__ att_chunk, const int* __restrict__ ei_src,
    const int* __restrict__ ei_tar, const bf16* __restrict__ Vc,
    const float* __restrict__ m_c, const float* __restrict__ m_n,
    const float* __restrict__ s_c, const float* __restrict__ s_s,
    float* hat_c, float* hat_s)
{
    int idx = blockIdx.x * 256 + threadIdx.x;
    if (idx >= E_PER_T * NH) return;
    int h = idx & 7;
    int e = idx >> 3;
    int src = ei_src[e];
    int tar = ei_tar[e];
    float a = att_chunk[idx];
    int nh = tar * NH + h;
    float pc = __expf(a - m_c[nh]) / (s_c[nh] + 1e-16f);
    float ps = __expf(m_n[nh] - a) / (s_s[nh] + 1e-16f);

    const uint4* vp = (const uint4*)(Vc + ((size_t)src * HID + h * DK));
    uint4 v0 = vp[0], v1 = vp[1];
    const unsigned* pv0 = (const unsigned*)&v0;
    const unsigned* pv1 = (const unsigned*)&v1;
    float* hc = hat_c + (size_t)tar * HID + h * DK;
    float* hs = hat_s + (size_t)tar * HID + h * DK;
#pragma unroll
    for (int i = 0; i < 4; ++i) {
        float vlo = __uint_as_float(pv0[i] << 16);
        float vhi = __uint_as_float(pv0[i] & 0xffff0000u);
        atomicAdd(&hc[2 * i + 0], vlo * pc);
        atomicAdd(&hc[2 * i + 1], vhi * pc);
        atomicAdd(&hs[2 * i + 0], vlo * ps);
        atomicAdd(&hs[2 * i + 1], vhi * ps);
    }
#pragma unroll
    for (int i = 0; i < 4; ++i) {
        float vlo = __uint_as_float(pv1[i] << 16);
        float vhi = __uint_as_float(pv1[i] & 0xffff0000u);
        atomicAdd(&hc[8 + 2 * i + 0], vlo * pc);
        atomicAdd(&hc[8 + 2 * i + 1], vhi * pc);
        atomicAdd(&hs[8 + 2 * i + 0], vlo * ps);
        atomicAdd(&hs[8 + 2 * i + 1], vhi * ps);
    }
}

// ---------------------------------------------------------------------------
// Kernel 6: FFN (LayerNorm -> 128x256 GELU -> 256x128, residual), in-place on
// hat buffers (fp32). blockIdx.y = branch (0 causal: +x residual; 1 spurious).
// ---------------------------------------------------------------------------
__global__ __launch_bounds__(256) void ffn_kernel(
    float* hat_c, float* hat_s, const float* __restrict__ x,
    const float* __restrict__ ln_s, const float* __restrict__ ln_b,
    const float* __restrict__ W1, const float* __restrict__ b1,
    const float* __restrict__ W2, const float* __restrict__ b2,
    int t_tar)
{
    const int br = blockIdx.y;
    float* hat = br ? hat_s : hat_c;
    const int n0 = blockIdx.x * 32;
    const int tid = threadIdx.x;

    __shared__ float hn[32][128];
    __shared__ float hid[32][256];
    __shared__ float mu_s[32], rs_s[32];

    // load h = hat (+ x for causal branch)
    for (int i = tid; i < 32 * 128; i += 256) {
        int r = i >> 7, c = i & 127;
        int n = n0 + r;
        float h = 0.f;
        if (n < N_NODES) {
            h = hat[(size_t)n * 128 + c];
            if (br == 0) h += x[((size_t)t_tar * N_NODES + n) * 128 + c];
        }
        hn[r][c] = h;
    }
    __syncthreads();

    // LayerNorm stats: 8 threads per row
    {
        int r = tid >> 3, l = tid & 7;
        float s = 0.f, s2 = 0.f;
#pragma unroll
        for (int d = l * 16; d < l * 16 + 16; ++d) {
            float v = hn[r][d];
            s += v; s2 += v * v;
        }
#pragma unroll
        for (int o = 4; o; o >>= 1) { s += __shfl_xor(s, o, 8); s2 += __shfl_xor(s2, o, 8); }
        if (l == 0) {
            float mu = s * (1.f / 128.f);
            float var = s2 * (1.f / 128.f) - mu * mu;
            mu_s[r] = mu;
            rs_s[r] = rsqrtf(var + 1e-5f);
        }
    }
    __syncthreads();

    for (int i = tid; i < 32 * 128; i += 256) {
        int r = i >> 7, c = i & 127;
        hn[r][c] = (hn[r][c] - mu_s[r]) * rs_s[r] * ln_s[c] + ln_b[c];
    }
    __syncthreads();

    // GEMM1: [32,128] @ [128,256] + b1, exact GELU
    {
        float acc[32];
#pragma unroll
        for (int r = 0; r < 32; ++r) acc[r] = 0.f;
        for (int k = 0; k < 128; k += 4) {
            float w0 = W1[(k + 0) * 256 + tid];
            float w1 = W1[(k + 1) * 256 + tid];
            float w2 = W1[(k + 2) * 256 + tid];
            float w3 = W1[(k + 3) * 256 + tid];
#pragma unroll
            for (int r = 0; r < 32; ++r) {
                const float4 hv = *(const float4*)&hn[r][k];
                acc[r] += hv.x * w0 + hv.y * w1 + hv.z * w2 + hv.w * w3;
            }
        }
        float bb = b1[tid];
#pragma unroll
        for (int r = 0; r < 32; ++r) {
            float z = acc[r] + bb;
            hid[r][tid] = 0.5f * z * (1.f + erff(z * 0.70710678118654752f));
        }
    }
    __syncthreads();

    // GEMM2: [32,256] @ [256,128] + b2; out = h + r, written in-place to hat
    {
        const int col = tid & 127;
        const int rg  = tid >> 7;  // 2 groups of 16 rows
        float acc[16];
#pragma unroll
        for (int j = 0; j < 16; ++j) acc[j] = 0.f;
        for (int k = 0; k < 256; k += 4) {
            float w0 = W2[(k + 0) * 128 + col];
            float w1 = W2[(k + 1) * 128 + col];
            float w2 = W2[(k + 2) * 128 + col];
            float w3 = W2[(k + 3) * 128 + col];
#pragma unroll
            for (int j = 0; j < 16; ++j) {
                int r = rg * 16 + j;
                const float4 hv = *(const float4*)&hid[r][k];
                acc[j] += hv.x * w0 + hv.y * w1 + hv.z * w2 + hv.w * w3;
            }
        }
        float bb = b2[col];
#pragma unroll
        for (int j = 0; j < 16; ++j) {
            int r = rg * 16 + j;
            int n = n0 + r;
            if (n < N_NODES) {
                float h = hat[(size_t)n * 128 + col];
                if (br == 0) h += x[((size_t)t_tar * N_NODES + n) * 128 + col];
                hat[(size_t)n * 128 + col] = h + acc[j] + bb;
            }
        }
    }
}

// ---------------------------------------------------------------------------
// Kernel 7: pack outputs: out[0]=c+s, out[1]=c, out[2]=s  ([3][T][1][N][128] fp32)
// ---------------------------------------------------------------------------
__global__ __launch_bounds__(256) void combine_kernel(
    const float* __restrict__ hat_c, const float* __restrict__ hat_s,
    float* __restrict__ out, int t_tar)
{
    size_t i = (size_t)blockIdx.x * 256 + threadIdx.x;
    if (i >= (size_t)N_NODES * HID) return;
    float c = hat_c[i], s = hat_s[i];
    const size_t TS = (size_t)T_WIN * N_NODES * HID;
    size_t o = (size_t)t_tar * N_NODES * HID + i;
    out[o]          = c + s;
    out[TS + o]     = c;
    out[2 * TS + o] = s;
}

extern "C" void kernel_launch(void* const* d_in, const int* in_sizes, int n_in,
                              void* d_out, int out_size, void* d_ws, size_t ws_size,
                              hipStream_t stream) {
    const float* x    = (const float*)d_in[0];
    const int*   ei   = (const int*)  d_in[1];
    const float* Wq   = (const float*)d_in[2];
    const float* bq   = (const float*)d_in[3];
    const float* Wk   = (const float*)d_in[4];
    const float* bk   = (const float*)d_in[5];
    const float* Wv   = (const float*)d_in[6];
    const float* bv   = (const float*)d_in[7];
    const float* ln_s = (const float*)d_in[8];
    const float* ln_b = (const float*)d_in[9];
    const float* W1   = (const float*)d_in[10];
    const float* b1   = (const float*)d_in[11];
    const float* W2   = (const float*)d_in[12];
    const float* b2   = (const float*)d_in[13];
    float* out = (float*)d_out;

    // ---- Workspace layout: 92.8 MB total ----
    const size_t NHID = (size_t)N_NODES * HID;   // 6,400,000
    float* hat_c = (float*)d_ws;                 // 25.6 MB
    float* hat_s = hat_c + NHID;                 // 25.6 MB
    float* att   = hat_s + NHID;                 // 9.6 MB  (3*E*NH fp32 max)
    float* m_c   = att + (size_t)T_WIN * E_PER_T * NH;
    float* m_n   = m_c + (size_t)N_NODES * NH;   // stats: 4 x 1.6 MB
    float* s_c   = m_n + (size_t)N_NODES * NH;
    float* s_s   = s_c + (size_t)N_NODES * NH;
    bf16*  Qt    = (bf16*)(s_s + (size_t)N_NODES * NH);  // 12.8 MB
    bf16*  KV    = Qt + NHID;                            // 12.8 MB (K then V per chunk)

    const int PROJ_BLOCKS = (N_NODES + 31) / 32;          // 1563
    const int CHUNK_BLOCKS = (E_PER_T * NH + 255) / 256;  // 3125

    for (int t = 0; t < T_WIN; ++t) {
        // Q for target timestep
        project_kernel<<<PROJ_BLOCKS, 256, 0, stream>>>(
            x + (size_t)t * NHID, Wq, bq, Qt);
        init_kernel<<<((int)NHID + 255) / 256, 256, 0, stream>>>(
            m_c, m_n, s_c, s_s, hat_c, hat_s);

        // attention logits per source timestep (K projected on the fly)
        for (int ts = 0; ts <= t; ++ts) {
            project_kernel<<<PROJ_BLOCKS, 256, 0, stream>>>(
                x + (size_t)ts * NHID, Wk, bk, KV);
            att_chunk_kernel<<<CHUNK_BLOCKS, 256, 0, stream>>>(
                Qt, KV,
                ei + (size_t)(ts * 2) * E_PER_T,
                ei + (size_t)(ts * 2 + 1) * E_PER_T,
                att + (size_t)ts * E_PER_T * NH, m_c, m_n);
        }

        int tot = (t + 1) * E_PER_T * NH;
        sum_kernel<<<(tot + 255) / 256, 256, 0, stream>>>(
            att, ei, m_c, m_n, s_c, s_s, t);

        // aggregation per source timestep (V projected on the fly into KV slot)
        for (int ts = 0; ts <= t; ++ts) {
            project_kernel<<<PROJ_BLOCKS, 256, 0, stream>>>(
                x + (size_t)ts * NHID, Wv, bv, KV);
            agg_chunk_kernel<<<CHUNK_BLOCKS, 256, 0, stream>>>(
                att + (size_t)ts * E_PER_T * NH,
                ei + (size_t)(ts * 2) * E_PER_T,
                ei + (size_t)(ts * 2 + 1) * E_PER_T,
                KV, m_c, m_n, s_c, s_s, hat_c, hat_s);
        }

        dim3 fg((N_NODES + 31) / 32, 2);
        ffn_kernel<<<fg, 256, 0, stream>>>(hat_c, hat_s, x, ln_s, ln_b, W1, b1, W2, b2, t);
        combine_kernel<<<((int)NHID + 255) / 256, 256, 0, stream>>>(hat_c, hat_s, out, t);
    }
}

// Round 4
// 2569.462 us; speedup vs baseline: 4.2557x; 4.2557x over previous
//
#include <hip/hip_runtime.h>
#include <hip/hip_bf16.h>
#include <math.h>

// Problem constants (from reference)
#define T_WIN   3
#define N_NODES 50000
#define HID     128
#define E_PER_T 100000
#define NH      8
#define DK      16

// R4: scatter-atomics (agg_chunk 6x1413us, WRITE 800MB/dispatch, VALUBusy 0.16%)
// replaced by CSR gather: one wave per node, zero atomics in the hot path.

typedef __hip_bfloat16 bf16;

// ---------------------------------------------------------------------------
// Kernel 1: O[r,:] = xrows[r,:] @ W + b  (fp32 in, bf16 out staging).
// ---------------------------------------------------------------------------
__global__ __launch_bounds__(256) void project_kernel(
    const float* __restrict__ xrows, const float* __restrict__ W,
    const float* __restrict__ b, bf16* __restrict__ O)
{
    __shared__ float xs[32][128];
    const int r0 = blockIdx.x * 32;
    const int tid = threadIdx.x;
    const int nrows = (N_NODES - r0 < 32) ? (N_NODES - r0) : 32;

    for (int i = tid; i < 32 * 32; i += 256) {
        int r = i >> 5, c4 = i & 31;
        float4 v = (r < nrows) ? ((const float4*)xrows)[(size_t)(r0 + r) * 32 + c4]
                               : make_float4(0.f, 0.f, 0.f, 0.f);
        *(float4*)&xs[r][c4 * 4] = v;
    }
    __syncthreads();

    const int col = tid & 127;
    const int rg  = tid >> 7;  // 0/1

    float acc[16];
#pragma unroll
    for (int j = 0; j < 16; ++j) acc[j] = 0.f;
    for (int k = 0; k < 128; k += 4) {
        float w0 = W[(k + 0) * 128 + col];
        float w1 = W[(k + 1) * 128 + col];
        float w2 = W[(k + 2) * 128 + col];
        float w3 = W[(k + 3) * 128 + col];
#pragma unroll
        for (int j = 0; j < 16; ++j) {
            const float4 hv = *(const float4*)&xs[rg + 2 * j][k];
            acc[j] += hv.x * w0 + hv.y * w1 + hv.z * w2 + hv.w * w3;
        }
    }
    float bias = b[col];
#pragma unroll
    for (int j = 0; j < 16; ++j) {
        int r = rg + 2 * j;
        if (r < nrows)
            O[(size_t)(r0 + r) * 128 + col] = __float2bfloat16(acc[j] + bias);
    }
}

// ---------------------------------------------------------------------------
// CSR build (once, before the t loop).
// ---------------------------------------------------------------------------
__global__ __launch_bounds__(256) void zero_counts_kernel(int* cursor)
{
    int i = blockIdx.x * 256 + threadIdx.x;
    if (i < T_WIN * N_NODES) cursor[i] = 0;
}

__global__ __launch_bounds__(256) void hist_kernel(
    const int* __restrict__ ei, int* counts)
{
    int i = blockIdx.x * 256 + threadIdx.x;
    if (i >= T_WIN * E_PER_T) return;
    int ts = i / E_PER_T;
    int e  = i - ts * E_PER_T;
    int tar = ei[(ts * 2 + 1) * E_PER_T + e];
    atomicAdd(&counts[ts * N_NODES + tar], 1);
}

// one block (1024 thr) per ts: exclusive scan of counts -> offs[ts][N+1]
__global__ __launch_bounds__(1024) void scan_kernel(
    const int* __restrict__ counts, int* __restrict__ offs)
{
    __shared__ int buf[1024];
    __shared__ int carry;
    const int ts = blockIdx.x;
    const int tid = threadIdx.x;
    if (tid == 0) carry = 0;
    __syncthreads();
    for (int base = 0; base < N_NODES; base += 1024) {
        int i = base + tid;
        int v = (i < N_NODES) ? counts[ts * N_NODES + i] : 0;
        buf[tid] = v;
        __syncthreads();
        for (int o = 1; o < 1024; o <<= 1) {
            int t = (tid >= o) ? buf[tid - o] : 0;
            __syncthreads();
            buf[tid] += t;
            __syncthreads();
        }
        int incl = buf[tid];
        if (i < N_NODES) offs[ts * (N_NODES + 1) + i] = carry + incl - v;
        __syncthreads();
        if (tid == 1023) carry += incl;
        __syncthreads();
    }
    if (tid == 0) offs[ts * (N_NODES + 1) + N_NODES] = carry;
}

__global__ __launch_bounds__(256) void copy_cursor_kernel(
    const int* __restrict__ offs, int* cursor)
{
    int i = blockIdx.x * 256 + threadIdx.x;
    if (i >= T_WIN * N_NODES) return;
    int ts = i / N_NODES;
    int n  = i - ts * N_NODES;
    cursor[i] = offs[ts * (N_NODES + 1) + n];
}

__global__ __launch_bounds__(256) void fill_kernel(
    const int* __restrict__ ei, int* cursor, int* __restrict__ eidbuf)
{
    int i = blockIdx.x * 256 + threadIdx.x;
    if (i >= T_WIN * E_PER_T) return;
    int ts = i / E_PER_T;
    int e  = i - ts * E_PER_T;
    int tar = ei[(ts * 2 + 1) * E_PER_T + e];
    int pos = atomicAdd(&cursor[ts * N_NODES + tar], 1);
    eidbuf[ts * E_PER_T + pos] = e;
}

// ---------------------------------------------------------------------------
// init hat accumulators per t.
// ---------------------------------------------------------------------------
__global__ __launch_bounds__(256) void init_hat_kernel(float* hat_c, float* hat_s)
{
    int i = blockIdx.x * 256 + threadIdx.x;
    if (i < N_NODES * HID) { hat_c[i] = 0.f; hat_s[i] = 0.f; }
}

// ---------------------------------------------------------------------------
// attention logits for ONE t_src chunk (no atomics).
// att layout: att[(ts*E + e)*NH + h]
// ---------------------------------------------------------------------------
__global__ __launch_bounds__(256) void att_chunk_kernel(
    const bf16* __restrict__ Qt, const bf16* __restrict__ Kc,
    const int* __restrict__ ei_src, const int* __restrict__ ei_tar,
    float* __restrict__ att_chunk)
{
    int idx = blockIdx.x * 256 + threadIdx.x;
    if (idx >= E_PER_T * NH) return;
    int h = idx & 7;
    int e = idx >> 3;
    int src = ei_src[e];
    int tar = ei_tar[e];

    const uint4* qp = (const uint4*)(Qt + ((size_t)tar * HID + h * DK));
    const uint4* kp = (const uint4*)(Kc + ((size_t)src * HID + h * DK));
    uint4 q0 = qp[0], q1 = qp[1];
    uint4 k0 = kp[0], k1 = kp[1];
    float s = 0.f;
    const unsigned* pa = (const unsigned*)&q0;
    const unsigned* pb = (const unsigned*)&k0;
#pragma unroll
    for (int i = 0; i < 4; ++i) {
        s += __uint_as_float(pa[i] << 16) * __uint_as_float(pb[i] << 16)
           + __uint_as_float(pa[i] & 0xffff0000u) * __uint_as_float(pb[i] & 0xffff0000u);
    }
    pa = (const unsigned*)&q1; pb = (const unsigned*)&k1;
#pragma unroll
    for (int i = 0; i < 4; ++i) {
        s += __uint_as_float(pa[i] << 16) * __uint_as_float(pb[i] << 16)
           + __uint_as_float(pa[i] & 0xffff0000u) * __uint_as_float(pb[i] & 0xffff0000u);
    }
    att_chunk[idx] = s * 0.25f;  // / sqrt(16)
}

// ---------------------------------------------------------------------------
// stats gather: one wave per node. lane = j8*8 + h (8 edge slots x 8 heads).
// Computes per-(node,head) max, min, exp-sums over ALL chunks ts<=t.
// ---------------------------------------------------------------------------
__global__ __launch_bounds__(256) void stats_gather_kernel(
    const float* __restrict__ att, const int* __restrict__ offs,
    const int* __restrict__ eidbuf,
    float* __restrict__ m_c, float* __restrict__ m_n,
    float* __restrict__ s_c, float* __restrict__ s_s, int t_tar)
{
    const int lane = threadIdx.x & 63;
    const int wave = threadIdx.x >> 6;
    const int node = blockIdx.x * 4 + wave;
    if (node >= N_NODES) return;
    const int h  = lane & 7;
    const int j8 = lane >> 3;

    float mx = -1e30f, mn = 1e30f;
    for (int ts = 0; ts <= t_tar; ++ts) {
        int beg = offs[ts * (N_NODES + 1) + node];
        int end = offs[ts * (N_NODES + 1) + node + 1];
        for (int j = beg + j8; j < end; j += 8) {
            int e = eidbuf[ts * E_PER_T + j];
            float a = att[((size_t)ts * E_PER_T + e) * NH + h];
            mx = fmaxf(mx, a);
            mn = fminf(mn, a);
        }
    }
#pragma unroll
    for (int o = 8; o < 64; o <<= 1) {
        mx = fmaxf(mx, __shfl_xor(mx, o));
        mn = fminf(mn, __shfl_xor(mn, o));
    }

    float sc = 0.f, ss = 0.f;
    for (int ts = 0; ts <= t_tar; ++ts) {
        int beg = offs[ts * (N_NODES + 1) + node];
        int end = offs[ts * (N_NODES + 1) + node + 1];
        for (int j = beg + j8; j < end; j += 8) {
            int e = eidbuf[ts * E_PER_T + j];
            float a = att[((size_t)ts * E_PER_T + e) * NH + h];
            sc += __expf(a - mx);
            ss += __expf(mn - a);
        }
    }
#pragma unroll
    for (int o = 8; o < 64; o <<= 1) {
        sc += __shfl_xor(sc, o);
        ss += __shfl_xor(ss, o);
    }

    if (j8 == 0) {
        m_c[node * NH + h] = mx;
        m_n[node * NH + h] = mn;
        s_c[node * NH + h] = sc;
        s_s[node * NH + h] = ss;
    }
}

// ---------------------------------------------------------------------------
// agg gather for ONE chunk: one wave per node, lane owns dims {2l, 2l+1}.
// Serial loop over the node's edges in this chunk; rmw hat in registers.
// ---------------------------------------------------------------------------
__global__ __launch_bounds__(256) void agg_gather_kernel(
    const float* __restrict__ att_chunk, const int* __restrict__ offs_ts,
    const int* __restrict__ eid_ts, const int* __restrict__ ei_src,
    const bf16* __restrict__ Vc,
    const float* __restrict__ m_c, const float* __restrict__ m_n,
    const float* __restrict__ s_c, const float* __restrict__ s_s,
    float* __restrict__ hat_c, float* __restrict__ hat_s)
{
    const int lane = threadIdx.x & 63;
    const int wave = threadIdx.x >> 6;
    const int node = blockIdx.x * 4 + wave;
    if (node >= N_NODES) return;

    const int beg = offs_ts[node];
    const int end = offs_ts[node + 1];
    if (beg == end) return;

    const int h = lane >> 3;   // dims 2l,2l+1 live in head (2l)/16 = l/8
    const int nh = node * NH + h;
    const float mc = m_c[nh];
    const float mn = m_n[nh];
    const float inv_sc = 1.f / (s_c[nh] + 1e-16f);
    const float inv_ss = 1.f / (s_s[nh] + 1e-16f);

    const size_t base = (size_t)node * HID + 2 * lane;
    float aC0 = hat_c[base], aC1 = hat_c[base + 1];
    float aS0 = hat_s[base], aS1 = hat_s[base + 1];

    for (int j = beg; j < end; ++j) {
        int e = eid_ts[j];
        float a = att_chunk[(size_t)e * NH + h];
        float pc = __expf(a - mc) * inv_sc;
        float ps = __expf(mn - a) * inv_ss;
        int src = ei_src[e];
        unsigned v2 = *(const unsigned*)(Vc + (size_t)src * HID + 2 * lane);
        float v0 = __uint_as_float(v2 << 16);
        float v1 = __uint_as_float(v2 & 0xffff0000u);
        aC0 += v0 * pc; aC1 += v1 * pc;
        aS0 += v0 * ps; aS1 += v1 * ps;
    }
    hat_c[base] = aC0; hat_c[base + 1] = aC1;
    hat_s[base] = aS0; hat_s[base + 1] = aS1;
}

// ---------------------------------------------------------------------------
// FFN (LayerNorm -> 128x256 GELU -> 256x128, residual), in-place on hat.
// blockIdx.y = branch (0 causal: +x residual; 1 spurious).
// ---------------------------------------------------------------------------
__global__ __launch_bounds__(256) void ffn_kernel(
    float* hat_c, float* hat_s, const float* __restrict__ x,
    const float* __restrict__ ln_s, const float* __restrict__ ln_b,
    const float* __restrict__ W1, const float* __restrict__ b1,
    const float* __restrict__ W2, const float* __restrict__ b2,
    int t_tar)
{
    const int br = blockIdx.y;
    float* hat = br ? hat_s : hat_c;
    const int n0 = blockIdx.x * 32;
    const int tid = threadIdx.x;

    __shared__ float hn[32][128];
    __shared__ float hid[32][256];
    __shared__ float mu_s[32], rs_s[32];

    for (int i = tid; i < 32 * 128; i += 256) {
        int r = i >> 7, c = i & 127;
        int n = n0 + r;
        float h = 0.f;
        if (n < N_NODES) {
            h = hat[(size_t)n * 128 + c];
            if (br == 0) h += x[((size_t)t_tar * N_NODES + n) * 128 + c];
        }
        hn[r][c] = h;
    }
    __syncthreads();

    {
        int r = tid >> 3, l = tid & 7;
        float s = 0.f, s2 = 0.f;
#pragma unroll
        for (int d = l * 16; d < l * 16 + 16; ++d) {
            float v = hn[r][d];
            s += v; s2 += v * v;
        }
#pragma unroll
        for (int o = 4; o; o >>= 1) { s += __shfl_xor(s, o, 8); s2 += __shfl_xor(s2, o, 8); }
        if (l == 0) {
            float mu = s * (1.f / 128.f);
            float var = s2 * (1.f / 128.f) - mu * mu;
            mu_s[r] = mu;
            rs_s[r] = rsqrtf(var + 1e-5f);
        }
    }
    __syncthreads();

    for (int i = tid; i < 32 * 128; i += 256) {
        int r = i >> 7, c = i & 127;
        hn[r][c] = (hn[r][c] - mu_s[r]) * rs_s[r] * ln_s[c] + ln_b[c];
    }
    __syncthreads();

    {
        float acc[32];
#pragma unroll
        for (int r = 0; r < 32; ++r) acc[r] = 0.f;
        for (int k = 0; k < 128; k += 4) {
            float w0 = W1[(k + 0) * 256 + tid];
            float w1 = W1[(k + 1) * 256 + tid];
            float w2 = W1[(k + 2) * 256 + tid];
            float w3 = W1[(k + 3) * 256 + tid];
#pragma unroll
            for (int r = 0; r < 32; ++r) {
                const float4 hv = *(const float4*)&hn[r][k];
                acc[r] += hv.x * w0 + hv.y * w1 + hv.z * w2 + hv.w * w3;
            }
        }
        float bb = b1[tid];
#pragma unroll
        for (int r = 0; r < 32; ++r) {
            float z = acc[r] + bb;
            hid[r][tid] = 0.5f * z * (1.f + erff(z * 0.70710678118654752f));
        }
    }
    __syncthreads();

    {
        const int col = tid & 127;
        const int rg  = tid >> 7;
        float acc[16];
#pragma unroll
        for (int j = 0; j < 16; ++j) acc[j] = 0.f;
        for (int k = 0; k < 256; k += 4) {
            float w0 = W2[(k + 0) * 128 + col];
            float w1 = W2[(k + 1) * 128 + col];
            float w2 = W2[(k + 2) * 128 + col];
            float w3 = W2[(k + 3) * 128 + col];
#pragma unroll
            for (int j = 0; j < 16; ++j) {
                int r = rg * 16 + j;
                const float4 hv = *(const float4*)&hid[r][k];
                acc[j] += hv.x * w0 + hv.y * w1 + hv.z * w2 + hv.w * w3;
            }
        }
        float bb = b2[col];
#pragma unroll
        for (int j = 0; j < 16; ++j) {
            int r = rg * 16 + j;
            int n = n0 + r;
            if (n < N_NODES) {
                float h = hat[(size_t)n * 128 + col];
                if (br == 0) h += x[((size_t)t_tar * N_NODES + n) * 128 + col];
                hat[(size_t)n * 128 + col] = h + acc[j] + bb;
            }
        }
    }
}

// ---------------------------------------------------------------------------
// pack outputs: out[0]=c+s, out[1]=c, out[2]=s  ([3][T][1][N][128] fp32)
// ---------------------------------------------------------------------------
__global__ __launch_bounds__(256) void combine_kernel(
    const float* __restrict__ hat_c, const float* __restrict__ hat_s,
    float* __restrict__ out, int t_tar)
{
    size_t i = (size_t)blockIdx.x * 256 + threadIdx.x;
    if (i >= (size_t)N_NODES * HID) return;
    float c = hat_c[i], s = hat_s[i];
    const size_t TS = (size_t)T_WIN * N_NODES * HID;
    size_t o = (size_t)t_tar * N_NODES * HID + i;
    out[o]          = c + s;
    out[TS + o]     = c;
    out[2 * TS + o] = s;
}

extern "C" void kernel_launch(void* const* d_in, const int* in_sizes, int n_in,
                              void* d_out, int out_size, void* d_ws, size_t ws_size,
                              hipStream_t stream) {
    const float* x    = (const float*)d_in[0];
    const int*   ei   = (const int*)  d_in[1];
    const float* Wq   = (const float*)d_in[2];
    const float* bq   = (const float*)d_in[3];
    const float* Wk   = (const float*)d_in[4];
    const float* bk   = (const float*)d_in[5];
    const float* Wv   = (const float*)d_in[6];
    const float* bv   = (const float*)d_in[7];
    const float* ln_s = (const float*)d_in[8];
    const float* ln_b = (const float*)d_in[9];
    const float* W1   = (const float*)d_in[10];
    const float* b1   = (const float*)d_in[11];
    const float* W2   = (const float*)d_in[12];
    const float* b2   = (const float*)d_in[13];
    float* out = (float*)d_out;

    // ---- Workspace layout: ~88.8 MB ----
    const size_t NHID = (size_t)N_NODES * HID;      // 6,400,000
    float* hat_c = (float*)d_ws;                    // 25.6 MB
    float* hat_s = hat_c + NHID;                    // 25.6 MB
    float* att   = hat_s + NHID;                    // 9.6 MB (T*E*NH fp32)
    float* m_c   = att + (size_t)T_WIN * E_PER_T * NH;
    float* m_n   = m_c + (size_t)N_NODES * NH;      // stats: 4 x 1.6 MB
    float* s_c   = m_n + (size_t)N_NODES * NH;
    float* s_s   = s_c + (size_t)N_NODES * NH;
    int*   offs   = (int*)(s_s + (size_t)N_NODES * NH); // 3*(N+1) ints
    int*   cursor = offs + T_WIN * (N_NODES + 1);       // 3*N ints (also counts)
    int*   eidbuf = cursor + T_WIN * N_NODES;           // 3*E ints
    bf16*  Qt     = (bf16*)(eidbuf + T_WIN * E_PER_T);  // 12.8 MB
    bf16*  KV     = Qt + NHID;                          // 12.8 MB

    const int PROJ_BLOCKS  = (N_NODES + 31) / 32;          // 1563
    const int EDGE_BLOCKS  = (E_PER_T * NH + 255) / 256;   // 3125
    const int NODE_BLOCKS  = (N_NODES + 3) / 4;            // 12500 (wave/node)
    const int TN_BLOCKS    = (T_WIN * N_NODES + 255) / 256;
    const int TE_BLOCKS    = (T_WIN * E_PER_T + 255) / 256;

    // ---- CSR build (edge targets independent of t_tar) ----
    zero_counts_kernel<<<TN_BLOCKS, 256, 0, stream>>>(cursor);
    hist_kernel<<<TE_BLOCKS, 256, 0, stream>>>(ei, cursor);
    scan_kernel<<<T_WIN, 1024, 0, stream>>>(cursor, offs);
    copy_cursor_kernel<<<TN_BLOCKS, 256, 0, stream>>>(offs, cursor);
    fill_kernel<<<TE_BLOCKS, 256, 0, stream>>>(ei, cursor, eidbuf);

    for (int t = 0; t < T_WIN; ++t) {
        project_kernel<<<PROJ_BLOCKS, 256, 0, stream>>>(
            x + (size_t)t * NHID, Wq, bq, Qt);
        init_hat_kernel<<<((int)NHID + 255) / 256, 256, 0, stream>>>(hat_c, hat_s);

        // attention logits per source timestep (K projected on the fly)
        for (int ts = 0; ts <= t; ++ts) {
            project_kernel<<<PROJ_BLOCKS, 256, 0, stream>>>(
                x + (size_t)ts * NHID, Wk, bk, KV);
            att_chunk_kernel<<<EDGE_BLOCKS, 256, 0, stream>>>(
                Qt, KV,
                ei + (size_t)(ts * 2) * E_PER_T,
                ei + (size_t)(ts * 2 + 1) * E_PER_T,
                att + (size_t)ts * E_PER_T * NH);
        }

        stats_gather_kernel<<<NODE_BLOCKS, 256, 0, stream>>>(
            att, offs, eidbuf, m_c, m_n, s_c, s_s, t);

        // aggregation per source timestep (V projected on the fly)
        for (int ts = 0; ts <= t; ++ts) {
            project_kernel<<<PROJ_BLOCKS, 256, 0, stream>>>(
                x + (size_t)ts * NHID, Wv, bv, KV);
            agg_gather_kernel<<<NODE_BLOCKS, 256, 0, stream>>>(
                att + (size_t)ts * E_PER_T * NH,
                offs + ts * (N_NODES + 1),
                eidbuf + ts * E_PER_T,
                ei + (size_t)(ts * 2) * E_PER_T,
                KV, m_c, m_n, s_c, s_s, hat_c, hat_s);
        }

        dim3 fg((N_NODES + 31) / 32, 2);
        ffn_kernel<<<fg, 256, 0, stream>>>(hat_c, hat_s, x, ln_s, ln_b, W1, b1, W2, b2, t);
        combine_kernel<<<((int)NHID + 255) / 256, 256, 0, stream>>>(hat_c, hat_s, out, t);
    }
}